// Round 4
// baseline (546.369 us; speedup 1.0000x reference)
//
#include <hip/hip_runtime.h>
#include <stdint.h>

#define V_DIM 32000
#define M_TOT 4096      // B*S
#define NF 128          // 2*n_freq
#define NC 256          // channels
#define BK 64
#define KSTEPS 500      // V_DIM / BK
#define NSPL 16         // k-splits
#define AROW 72         // A LDS row stride in bf16 elems (144 B -> +4 banks/row rotation)
#define THREADS 256

typedef __bf16 bf16x8 __attribute__((ext_vector_type(8)));
typedef float f32x4 __attribute__((ext_vector_type(4)));

__device__ __forceinline__ unsigned short f2bf(float f) {   // RNE, table build only
  unsigned int u = __float_as_uint(f);
  u += 0x7FFFu + ((u >> 16) & 1u);
  return (unsigned short)(u >> 16);
}

// pack two fp32 -> bf16x2 by truncation: 1 v_perm per pair
__device__ __forceinline__ unsigned int pk2(float lo, float hi) {
  return __builtin_amdgcn_perm(__float_as_uint(hi), __float_as_uint(lo), 0x07060302u);
}

// ---------------- Stage 0: DFT basis in B-FRAGMENT order ----------------
// elem addr = (((c2*4) + kgl)*128 + n)*8 + e , c2 in [0,1000) = 32-wide k-chunk
//   value = T_log[n][c2*32 + kgl*8 + e]
//   T_log[f][v] = cos(2pi(f+1)v/V) f<64 ; -sin(2pi(f-63)v/V) f>=64
// gemm1 lane (kgl,rl) reads its bf16x8 B-fragment as ONE contiguous 16B global load.
__global__ __launch_bounds__(256) void build_table(unsigned short* __restrict__ T) {
  int id = blockIdx.x * 256 + threadIdx.x;   // slot id
  if (id >= 512000) return;
  int n = id & 127;
  int g = id >> 7;
  int kgl = g & 3;
  int c2 = g >> 2;                           // 0..999
  int vb = c2 * 32 + kgl * 8;
  int k = (n < 64) ? (n + 1) : (n - 63);
  bool is_cos = (n < 64);
  const float w0 = 6.283185307179586f / (float)V_DIM;
  union { unsigned short us[8]; uint4 v; } u;
  #pragma unroll
  for (int e = 0; e < 8; ++e) {
    int m = (k * (vb + e)) % V_DIM;          // exact range reduction
    float s, cc;
    __sincosf((float)m * w0, &s, &cc);
    u.us[e] = f2bf(is_cos ? cc : -s);
  }
  *reinterpret_cast<uint4*>(T + (size_t)id * 8) = u.v;
}

// ---------------- Stage 1: P[ks] = x @ T^T, tile 128m x 64n, BK=64 ----------------
__global__ __launch_bounds__(THREADS, 4) void gemm1(
    const float* __restrict__ x, const unsigned short* __restrict__ T,
    float* __restrict__ P) {
  __shared__ __align__(16) unsigned short As[2][128 * AROW];  // 18 KB per buf

  // decode: XCD j gets pid ≡ j (mod 8); nt pairs adjacent in dispatch order
  const int b = blockIdx.x;
  const int j = b & 7, q = b >> 3;
  const int nt = q & 1;
  const int lid = q >> 1;            // 0..63
  const int pid = j + 8 * lid;       // 0..511
  const int ks = pid & 15;           // per XCD only 2 distinct ks -> tiny T set in L2
  const int mt = pid >> 4;           // 0..31
  const int m0 = mt * 128;

  const int basek = KSTEPS / NSPL, remk = KSTEPS % NSPL;
  const int steps = basek + (ks < remk);
  const int start = ks * basek + (ks < remk ? ks : remk);

  const int t = threadIdx.x;
  const int lane = t & 63, wave = t >> 6;
  const int wm = wave >> 1, wn = wave & 1;   // 2x2 waves, wave tile 64m x 32n
  const int kgl = lane >> 4, rl = lane & 15;

  const int row_t = t >> 1, half = t & 1;    // 2 threads/row, 128B contiguous each
  const float* xa = x + (size_t)(m0 + row_t) * V_DIM + half * 32 + (size_t)start * BK;
  const int wbase = row_t * AROW + half * 32;

  // B fragment base for (s=0, kk=0, nf=0); offsets: kk +4096, nf +128, step +8192
  const unsigned short* tb = T + ((size_t)(start * 8 + kgl) * 128
                                  + (nt * 64 + wn * 32 + rl)) * 8;

  f32x4 acc[4][2];
  #pragma unroll
  for (int i = 0; i < 4; ++i)
    #pragma unroll
    for (int jn = 0; jn < 2; ++jn) acc[i][jn] = (f32x4){0.f, 0.f, 0.f, 0.f};

  bf16x8 bvA[2][2], bvB[2][2];   // named double-buffered B-fragment sets

  // ---- prologue: stage x(0) -> buf0, load bv(0)
  {
    float4 xv[8];
    #pragma unroll
    for (int i = 0; i < 8; ++i)
      xv[i] = *reinterpret_cast<const float4*>(xa + i * 4);
    #pragma unroll
    for (int kk = 0; kk < 2; ++kk)
      #pragma unroll
      for (int nf = 0; nf < 2; ++nf)
        bvA[kk][nf] = *reinterpret_cast<const bf16x8*>(tb + kk * 4096 + nf * 128);
    #pragma unroll
    for (int i = 0; i < 4; ++i) {
      uint4 w;
      w.x = pk2(xv[2 * i].x, xv[2 * i].y);
      w.y = pk2(xv[2 * i].z, xv[2 * i].w);
      w.z = pk2(xv[2 * i + 1].x, xv[2 * i + 1].y);
      w.w = pk2(xv[2 * i + 1].z, xv[2 * i + 1].w);
      *reinterpret_cast<uint4*>(&As[0][wbase + i * 8]) = w;
    }
    __syncthreads();
  }

  int s = 0;
#define STEP(CUR, NXT, BVC, BVN)                                              \
  {                                                                           \
    const bool pre = (s + 1 < steps);                                         \
    float4 xv[8];                                                             \
    if (pre) { /* issue all next-step globals first */                        \
      const float* xp = xa + (size_t)(s + 1) * BK;                            \
      _Pragma("unroll")                                                       \
      for (int i = 0; i < 8; ++i)                                             \
        xv[i] = *reinterpret_cast<const float4*>(xp + i * 4);                 \
      const unsigned short* tp = tb + (size_t)(s + 1) * 8192;                 \
      _Pragma("unroll")                                                       \
      for (int kk = 0; kk < 2; ++kk)                                          \
        _Pragma("unroll")                                                     \
        for (int nf = 0; nf < 2; ++nf)                                        \
          BVN[kk][nf] =                                                       \
              *reinterpret_cast<const bf16x8*>(tp + kk * 4096 + nf * 128);    \
    }                                                                         \
    _Pragma("unroll")                                                         \
    for (int kk = 0; kk < 2; ++kk)                                            \
      _Pragma("unroll")                                                       \
      for (int mf = 0; mf < 4; ++mf) {                                        \
        bf16x8 av = *reinterpret_cast<const bf16x8*>(                         \
            &As[CUR][(wm * 64 + mf * 16 + rl) * AROW + kk * 32 + kgl * 8]);   \
        _Pragma("unroll")                                                     \
        for (int nf = 0; nf < 2; ++nf)                                        \
          acc[mf][nf] = __builtin_amdgcn_mfma_f32_16x16x32_bf16(              \
              av, BVC[kk][nf], acc[mf][nf], 0, 0, 0);                         \
      }                                                                       \
    if (pre) { /* consume x loads late: vmcnt wait covered by MFMAs above */  \
      _Pragma("unroll")                                                       \
      for (int i = 0; i < 4; ++i) {                                           \
        uint4 w;                                                              \
        w.x = pk2(xv[2 * i].x, xv[2 * i].y);                                  \
        w.y = pk2(xv[2 * i].z, xv[2 * i].w);                                  \
        w.z = pk2(xv[2 * i + 1].x, xv[2 * i + 1].y);                          \
        w.w = pk2(xv[2 * i + 1].z, xv[2 * i + 1].w);                          \
        *reinterpret_cast<uint4*>(&As[NXT][wbase + i * 8]) = w;               \
      }                                                                       \
    }                                                                         \
    __syncthreads();                                                          \
  }

  while (true) {
    STEP(0, 1, bvA, bvB)
    if (++s >= steps) break;
    STEP(1, 0, bvB, bvA)
    if (++s >= steps) break;
  }
#undef STEP

  // ---- epilogue: partial [128 x 64] at col offset nt*64
  float* Pp = P + ((size_t)ks * M_TOT + m0) * NF + nt * 64 + wn * 32;
  const int r0 = (lane >> 4) * 4;
  #pragma unroll
  for (int mf = 0; mf < 4; ++mf)
    #pragma unroll
    for (int nf = 0; nf < 2; ++nf)
      #pragma unroll
      for (int jj = 0; jj < 4; ++jj)
        Pp[(size_t)(wm * 64 + mf * 16 + r0 + jj) * NF + nf * 16 + rl] =
            acc[mf][nf][jj];
}

// ---------------- Stage 2: out = (sum_s P[s]) @ W^T ----------------
__global__ __launch_bounds__(256) void gemm2(
    const float* __restrict__ P, const float* __restrict__ W,
    float* __restrict__ out, int NS) {
  __shared__ __align__(16) float Xr[8][NF];
  const int mb = blockIdx.x * 8;
  const int t = threadIdx.x;

  #pragma unroll
  for (int i = 0; i < 4; ++i) {
    int idx = t + i * 256;           // 8 rows x 128 freqs
    int r = idx >> 7, f = idx & 127;
    float s = 0.f;
    for (int sp = 0; sp < NS; ++sp)
      s += P[((size_t)sp * M_TOT + mb + r) * NF + f];
    Xr[r][f] = s;
  }
  __syncthreads();

  const float4* Wr = reinterpret_cast<const float4*>(W + (size_t)t * NF);
  float accr[8];
  #pragma unroll
  for (int r = 0; r < 8; ++r) accr[r] = 0.f;

  for (int f4 = 0; f4 < NF / 4; ++f4) {
    float4 w = Wr[f4];
    #pragma unroll
    for (int r = 0; r < 8; ++r) {
      float4 xv = *reinterpret_cast<const float4*>(&Xr[r][f4 * 4]);
      accr[r] += xv.x * w.x + xv.y * w.y + xv.z * w.z + xv.w * w.w;
    }
  }
  #pragma unroll
  for (int r = 0; r < 8; ++r)
    out[(size_t)(mb + r) * NC + t] = accr[r];
}

extern "C" void kernel_launch(void* const* d_in, const int* in_sizes, int n_in,
                              void* d_out, int out_size, void* d_ws, size_t ws_size,
                              hipStream_t stream) {
  const float* x = (const float*)d_in[0];
  const float* w = (const float*)d_in[1];
  float* out = (float*)d_out;

  unsigned short* T = (unsigned short*)d_ws;
  const size_t t_bytes = (size_t)NF * V_DIM * sizeof(unsigned short); // 8,192,000
  float* P = (float*)((char*)d_ws + t_bytes);
  // P: NSPL * 2 MiB = 32 MiB; total ws need = 40 MiB (R3 proved >= 72 MiB available)

  build_table<<<dim3(2000), dim3(256), 0, stream>>>(T);
  gemm1<<<dim3(32 * 2 * NSPL), dim3(THREADS), 0, stream>>>(x, T, P);
  gemm2<<<dim3(M_TOT / 8), dim3(256), 0, stream>>>(P, w, out, NSPL);
}

// Round 5
// 159.064 us; speedup vs baseline: 3.4349x; 3.4349x over previous
//
#include <hip/hip_runtime.h>
#include <stdint.h>

#define V_DIM 32000
#define M_TOT 4096      // B*S
#define NF 128          // 2*n_freq
#define NC 256          // channels
#define BM 64           // M-tile (64 mt tiles)
#define BK 32
#define KSTEPS 1000     // V_DIM / BK
#define NSPL 16
#define ASTR 66         // A slot stride per kg-plane (slots of 16B): +8 bank rotation
#define BSTR 130        // B slot stride per kg-plane: +8 bank rotation
#define THREADS 256

typedef __bf16 bf16x8 __attribute__((ext_vector_type(8)));
typedef float f32x4 __attribute__((ext_vector_type(4)));

__device__ __forceinline__ unsigned short f2bf(float f) {  // RNE
  unsigned int u = __float_as_uint(f);
  u += 0x7FFFu + ((u >> 16) & 1u);
  return (unsigned short)(u >> 16);
}

__device__ __forceinline__ int4 pack8(float4 lo, float4 hi) {
  union { unsigned short us[8]; int4 v; } u;
  u.us[0] = f2bf(lo.x); u.us[1] = f2bf(lo.y);
  u.us[2] = f2bf(lo.z); u.us[3] = f2bf(lo.w);
  u.us[4] = f2bf(hi.x); u.us[5] = f2bf(hi.y);
  u.us[6] = f2bf(hi.z); u.us[7] = f2bf(hi.w);
  return u.v;
}

// ---------------- Stage 0: DFT basis table in THREAD-STAGING order ----------------
// T_stage[c][q*256 + t] = 8 bf16; element e -> T_logical[row][c*32 + kg*8 + e]
//   row = (t>>2) + 64*q, kg = t&3
//   T_logical[f][v] = cos(2pi(f+1)v/V) f<64 ; -sin(2pi(f-63)v/V) f>=64
__global__ __launch_bounds__(256) void build_table(unsigned short* __restrict__ T) {
  int id = blockIdx.x * 256 + threadIdx.x;        // slot id, 512 per chunk
  if (id >= 512 * KSTEPS) return;                 // 512000
  int c = id >> 9;
  int r = id & 511;
  int q = r >> 8;
  int tt = r & 255;
  int row = (tt >> 2) + 64 * q;
  int kg = tt & 3;
  int k = (row < 64) ? (row + 1) : (row - 63);
  bool is_cos = (row < 64);
  int vb = c * 32 + kg * 8;
  const float w0 = 6.283185307179586f / (float)V_DIM;
  union { unsigned short us[8]; int4 v; } u;
  #pragma unroll
  for (int e = 0; e < 8; ++e) {
    int m = (k * (vb + e)) % V_DIM;               // exact range reduction
    float s, cc;
    __sincosf((float)m * w0, &s, &cc);
    u.us[e] = f2bf(is_cos ? cc : -s);
  }
  *reinterpret_cast<int4*>(T + (size_t)id * 8) = u.v;
}

// ---------------- Stage 1: P[ks] = x_tile @ T_chunk^T ----------------
// R1-proven schedule, BM=64, 1024 blocks = 4/CU. NO waves/EU floor (R4 lesson).
__global__ __launch_bounds__(THREADS) void gemm1(
    const float* __restrict__ x, const unsigned short* __restrict__ T,
    float* __restrict__ P) {
  __shared__ __align__(16) unsigned short As[2][4 * ASTR * 8];  // 4224 B / buf
  __shared__ __align__(16) unsigned short Bs[2][4 * BSTR * 8];  // 8320 B / buf

  // XCD j (b&7) hosts only ks in {j, j+8} -> ~1MB of T per XCD L2
  const int b = blockIdx.x;
  const int j = b & 7, i = b >> 3;      // i: 0..127
  const int ks = j + 8 * (i & 1);
  const int mt = i >> 1;                // 0..63
  const int m0 = mt * BM;

  const int basek = KSTEPS / NSPL, remk = KSTEPS % NSPL;  // 62, 8
  const int steps = basek + (ks < remk);
  const int start = ks * basek + (ks < remk ? ks : remk);

  const int t = threadIdx.x;
  const int lane = t & 63, wave = t >> 6;
  const int wm = wave >> 1, wn = wave & 1;   // wave tile 32m x 64n
  const int kgl = lane >> 4, rl = lane & 15;

  const int kg_t = t & 3;
  const int row_t = t >> 2;                  // 0..63 (one A slot per thread)
  const int aslot = kg_t * ASTR + row_t;
  const int bslot0 = kg_t * BSTR + row_t;    // staged slot (kg,row)
  const int bslot1 = bslot0 + 64;            // (kg, row+64)

  const float* xa = x + (size_t)(m0 + row_t) * V_DIM + kg_t * 8 + (size_t)start * BK;
  const unsigned short* Tc = T + (size_t)start * 4096;

  f32x4 acc[2][4];
  #pragma unroll
  for (int a = 0; a < 2; ++a)
    #pragma unroll
    for (int c = 0; c < 4; ++c) acc[a][c] = (f32x4){0.f, 0.f, 0.f, 0.f};

  // ---- prologue: stage step 0 into buf0
  {
    float4 a0 = *reinterpret_cast<const float4*>(xa);
    float4 a1 = *reinterpret_cast<const float4*>(xa + 4);
    int4 b0 = *reinterpret_cast<const int4*>(Tc + t * 8);
    int4 b1 = *reinterpret_cast<const int4*>(Tc + (256 + t) * 8);
    *reinterpret_cast<int4*>(&As[0][aslot * 8]) = pack8(a0, a1);
    *reinterpret_cast<int4*>(&Bs[0][bslot0 * 8]) = b0;
    *reinterpret_cast<int4*>(&Bs[0][bslot1 * 8]) = b1;
    __syncthreads();
  }

  for (int s = 0; s < steps; ++s) {
    const int cur = s & 1, nxt = cur ^ 1;
    const bool pre = (s + 1 < steps);

    // 1) issue next step's 4 global loads first (latency overlapped by MFMAs)
    float4 a0, a1;
    int4 b0, b1;
    if (pre) {
      const float* xp = xa + (size_t)(s + 1) * BK;
      a0 = *reinterpret_cast<const float4*>(xp);
      a1 = *reinterpret_cast<const float4*>(xp + 4);
      const unsigned short* tc = Tc + (size_t)(s + 1) * 4096;
      b0 = *reinterpret_cast<const int4*>(tc + t * 8);
      b1 = *reinterpret_cast<const int4*>(tc + (256 + t) * 8);
    }

    // 2) fragments + MFMA on current buffer
    bf16x8 bv[4];
    #pragma unroll
    for (int nf = 0; nf < 4; ++nf)
      bv[nf] = *reinterpret_cast<const bf16x8*>(
          &Bs[cur][(kgl * BSTR + wn * 64 + nf * 16 + rl) * 8]);
    #pragma unroll
    for (int mf = 0; mf < 2; ++mf) {
      bf16x8 av = *reinterpret_cast<const bf16x8*>(
          &As[cur][(kgl * ASTR + wm * 32 + mf * 16 + rl) * 8]);
      #pragma unroll
      for (int nf = 0; nf < 4; ++nf)
        acc[mf][nf] = __builtin_amdgcn_mfma_f32_16x16x32_bf16(
            av, bv[nf], acc[mf][nf], 0, 0, 0);
    }

    // 3) consume loads mid-step (vmcnt wait covered by MFMA issue above)
    if (pre) {
      *reinterpret_cast<int4*>(&As[nxt][aslot * 8]) = pack8(a0, a1);
      *reinterpret_cast<int4*>(&Bs[nxt][bslot0 * 8]) = b0;
      *reinterpret_cast<int4*>(&Bs[nxt][bslot1 * 8]) = b1;
    }
    __syncthreads();
  }

  // ---- epilogue: partial [64 x 128] tile for this k-split
  float* Pp = P + ((size_t)ks * M_TOT + m0) * NF;
  const int r0 = (lane >> 4) * 4;
  const int col = lane & 15;
  #pragma unroll
  for (int mf = 0; mf < 2; ++mf)
    #pragma unroll
    for (int nf = 0; nf < 4; ++nf)
      #pragma unroll
      for (int q = 0; q < 4; ++q) {
        int row = wm * 32 + mf * 16 + r0 + q;
        int n = wn * 64 + nf * 16 + col;
        Pp[(size_t)row * NF + n] = acc[mf][nf][q];
      }
}

// ---------------- Stage 2: out = (sum_s P[s]) @ W^T ----------------
__global__ __launch_bounds__(256) void gemm2(
    const float* __restrict__ P, const float* __restrict__ W,
    float* __restrict__ out, int NS) {
  __shared__ __align__(16) float Xr[8][NF];
  const int mb = blockIdx.x * 8;
  const int t = threadIdx.x;

  #pragma unroll
  for (int i = 0; i < 4; ++i) {
    int idx = t + i * 256;           // 8 rows x 128 freqs
    int r = idx >> 7, f = idx & 127;
    float s = 0.f;
    for (int sp = 0; sp < NS; ++sp)
      s += P[((size_t)sp * M_TOT + mb + r) * NF + f];
    Xr[r][f] = s;
  }
  __syncthreads();

  const float4* Wr = reinterpret_cast<const float4*>(W + (size_t)t * NF);
  float accr[8];
  #pragma unroll
  for (int r = 0; r < 8; ++r) accr[r] = 0.f;

  for (int f4 = 0; f4 < NF / 4; ++f4) {
    float4 w = Wr[f4];
    #pragma unroll
    for (int r = 0; r < 8; ++r) {
      float4 xv = *reinterpret_cast<const float4*>(&Xr[r][f4 * 4]);
      accr[r] += xv.x * w.x + xv.y * w.y + xv.z * w.z + xv.w * w.w;
    }
  }
  #pragma unroll
  for (int r = 0; r < 8; ++r)
    out[(size_t)(mb + r) * NC + t] = accr[r];
}

extern "C" void kernel_launch(void* const* d_in, const int* in_sizes, int n_in,
                              void* d_out, int out_size, void* d_ws, size_t ws_size,
                              hipStream_t stream) {
  const float* x = (const float*)d_in[0];
  const float* w = (const float*)d_in[1];
  float* out = (float*)d_out;

  unsigned short* T = (unsigned short*)d_ws;
  const size_t t_bytes = (size_t)NF * V_DIM * sizeof(unsigned short); // 8,192,000
  float* P = (float*)((char*)d_ws + t_bytes);
  // ws need: 8 MB (T) + 32 MB (P) = 40 MB. R3 ran with >= 72 MB available.

  build_table<<<dim3(2000), dim3(256), 0, stream>>>(T);
  gemm1<<<dim3(64 * NSPL), dim3(THREADS), 0, stream>>>(x, T, P);
  gemm2<<<dim3(M_TOT / 8), dim3(256), 0, stream>>>(P, w, out, NSPL);
}